// Round 8
// baseline (1470.176 us; speedup 1.0000x reference)
//
#include <hip/hip_runtime.h>
#include <cstdint>
#include <cstddef>

#define Nn 102400
#define Ff 400
#define Ee 1638400
#define Kk 300
#define Bb 256
#define CAP 64

// ---------------- CSR build: fill counts degree; csr rows filled atomically ----
__global__ void scat_k(const int* __restrict__ ei, int* __restrict__ fill,
                       int* __restrict__ csr) {
    int e = blockIdx.x * 256 + threadIdx.x;
    if (e >= Ee) return;
    int s = ei[e], d = ei[Ee + e];
    int p = atomicAdd(&fill[d], 1);
    if (p < CAP) csr[(size_t)d * CAP + p] = s;
}

// Deterministic row order + dis computation (deg == fill after scat_k).
__global__ __launch_bounds__(256) void sortrow_k(const int* __restrict__ deg,
                                                 int* __restrict__ csr,
                                                 double* __restrict__ dis) {
    int lane = threadIdx.x & 63;
    int v = blockIdx.x * 4 + (threadIdx.x >> 6);
    int dvf = deg[v];
    int dv = min(dvf, CAP);
    if (lane == 0) dis[v] = 1.0 / sqrt((double)(dvf + 1));   // +1 self loop
    int key = (lane < dv) ? csr[(size_t)v * CAP + lane] : 0x7FFFFFFF;
#pragma unroll
    for (int k = 2; k <= 64; k <<= 1) {
#pragma unroll
        for (int j = k >> 1; j; j >>= 1) {
            int other = __shfl_xor(key, j);
            bool up = ((lane & k) == 0);
            bool lower = ((lane & j) == 0);
            key = (lower == up) ? min(key, other) : max(key, other);
        }
    }
    if (lane < dv) csr[(size_t)v * CAP + lane] = key;
}

// ---- double-buffered GEMM: [M,K]@[K,64] fp64 accumulate, 64x64 tile, 256 thr,
// 4x4 per thread. One barrier per 16-k chunk; next chunk's global loads issue
// before compute (latency hidden). A staged in source precision (f32 layer 1:
// half DS traffic, exact cvt at use). Per output strictly one fma per k,
// ascending -> h-chain bit-identical to all previous rounds.
template <typename AT, int CH>   // K = 16*CH
__global__ __launch_bounds__(256) void gemm_db(const AT* __restrict__ A,
                                               const float* __restrict__ B,
                                               double* __restrict__ C) {
    constexpr int K = 16 * CH;
    constexpr bool F32 = (sizeof(AT) == 4);
    constexpr int APD = F32 ? 76 : 65;     // pads chosen for 2-way-max staging
    __shared__ __align__(16) AT As[2][16 * APD];
    __shared__ __align__(16) double Bs[2][16 * 65];
    int tid = threadIdx.x;
    int tx = tid & 15;            // cols {tx*2, tx*2+1, 32+tx*2, 33+tx*2}
    int ty = tid >> 4;            // rows ty*4..+3
    int base = blockIdx.x * 64;
    int sr = tid >> 2, sh = tid & 3;       // A staging: row sr, k-quad sh
    int bk = tid >> 4, bn = (tid & 15) * 4; // B staging
    double acc[4][4] = {};

    AT ar[4];
    float4 br;
    const AT* ap0 = A + (size_t)(base + sr) * K + sh * 4;
    const float* bp0 = B + (size_t)bk * 64 + bn;
    // preload chunk 0
    *(float4*)&br = *(const float4*)(bp0);
    if constexpr (F32) {
        float4 v = *(const float4*)(ap0);
        ar[0] = v.x; ar[1] = v.y; ar[2] = v.z; ar[3] = v.w;
    } else {
        double2 d0 = *(const double2*)(ap0);
        double2 d1 = *(const double2*)(ap0 + 2);
        ar[0] = d0.x; ar[1] = d0.y; ar[2] = d1.x; ar[3] = d1.y;
    }

    int p = 0;
    for (int ch = 0; ch < CH; ++ch) {
        // store staged regs into buffer p
        AT* asw = &As[p][0];
        double* bsw = &Bs[p][0];
#pragma unroll
        for (int q = 0; q < 4; ++q) asw[(sh * 4 + q) * APD + sr] = ar[q];
        bsw[bk * 65 + bn + 0] = (double)br.x;
        bsw[bk * 65 + bn + 1] = (double)br.y;
        bsw[bk * 65 + bn + 2] = (double)br.z;
        bsw[bk * 65 + bn + 3] = (double)br.w;
        __syncthreads();
        // issue next chunk's global loads (consumed after next barrier)
        if (ch + 1 < CH) {
            const AT* ap = ap0 + (ch + 1) * 16;
            const float* bp = bp0 + (size_t)(ch + 1) * 16 * 64;
            *(float4*)&br = *(const float4*)(bp);
            if constexpr (F32) {
                float4 v = *(const float4*)(ap);
                ar[0] = v.x; ar[1] = v.y; ar[2] = v.z; ar[3] = v.w;
            } else {
                double2 d0 = *(const double2*)(ap);
                double2 d1 = *(const double2*)(ap + 2);
                ar[0] = d0.x; ar[1] = d0.y; ar[2] = d1.x; ar[3] = d1.y;
            }
        }
        // compute on buffer p
#pragma unroll
        for (int kk = 0; kk < 16; ++kk) {
            double av[4];
            if constexpr (F32) {
                float4 a = *(const float4*)&asw[kk * APD + ty * 4];
                av[0] = a.x; av[1] = a.y; av[2] = a.z; av[3] = a.w;
            } else {
                double2 a01 = *(const double2*)&asw[kk * APD + ty * 4];
                double2 a23 = *(const double2*)&asw[kk * APD + ty * 4 + 2];
                av[0] = a01.x; av[1] = a01.y; av[2] = a23.x; av[3] = a23.y;
            }
            double2 b01 = *(const double2*)&bsw[kk * 65 + tx * 2];
            double2 b23 = *(const double2*)&bsw[kk * 65 + 32 + tx * 2];
            double bv[4] = {b01.x, b01.y, b23.x, b23.y};
#pragma unroll
            for (int r = 0; r < 4; ++r)
#pragma unroll
                for (int c = 0; c < 4; ++c) acc[r][c] += av[r] * bv[c];
        }
        p ^= 1;
        __syncthreads();
    }
#pragma unroll
    for (int r = 0; r < 4; ++r) {
        double* cp = C + (size_t)(base + ty * 4 + r) * 64;
        *(double2*)(cp + tx * 2)      = make_double2(acc[r][0], acc[r][1]);
        *(double2*)(cp + 32 + tx * 2) = make_double2(acc[r][2], acc[r][3]);
    }
}

// ------- out = tanh(bias + dsv*(sum_u du*t[u] + dsv*t[v])), 64-wide fp64 -------
// Unroll 16: 16 independent 512B row-gathers in flight per wave.
// fma order: j ascending, self-loop last — identical to all previous rounds.
__global__ __launch_bounds__(256) void agg64_k(const double* __restrict__ t,
                                               const float* __restrict__ bias,
                                               const double* __restrict__ dis,
                                               const int* __restrict__ deg,
                                               const int* __restrict__ csr,
                                               double* __restrict__ out,
                                               const float* __restrict__ W4,
                                               double* __restrict__ t4) {
    int lane = threadIdx.x & 63;
    int wv = __builtin_amdgcn_readfirstlane(threadIdx.x >> 6);
    int v = blockIdx.x * 4 + wv;
    int dv = min(deg[v], CAP);
    double dsv = dis[v];
    const int* row = csr + (size_t)v * CAP;
    double acc = 0.0;
    int j = 0;
    for (; j + 16 <= dv; j += 16) {
        int u[16]; double d[16], tv[16];
#pragma unroll
        for (int q = 0; q < 16; ++q) u[q] = row[j + q];
#pragma unroll
        for (int q = 0; q < 16; ++q) tv[q] = t[(size_t)u[q] * 64 + lane];
#pragma unroll
        for (int q = 0; q < 16; ++q) d[q] = dis[u[q]];
#pragma unroll
        for (int q = 0; q < 16; ++q) acc += d[q] * tv[q];
    }
    for (; j + 4 <= dv; j += 4) {
        int u[4]; double d[4], tv[4];
#pragma unroll
        for (int q = 0; q < 4; ++q) u[q] = row[j + q];
#pragma unroll
        for (int q = 0; q < 4; ++q) tv[q] = t[(size_t)u[q] * 64 + lane];
#pragma unroll
        for (int q = 0; q < 4; ++q) d[q] = dis[u[q]];
#pragma unroll
        for (int q = 0; q < 4; ++q) acc += d[q] * tv[q];
    }
    for (; j < dv; ++j) {
        int u = row[j];
        acc += dis[u] * t[(size_t)u * 64 + lane];
    }
    acc += dsv * t[(size_t)v * 64 + lane];   // self-loop last (ref appends loops)
    double res = tanh((double)bias[lane] + dsv * acc);
    out[(size_t)v * 64 + lane] = res;
    if (t4 != nullptr) {
        double x = res * (double)W4[lane];
#pragma unroll
        for (int o = 32; o > 0; o >>= 1) x += __shfl_xor(x, o);
        if (lane == 0) t4[v] = x;
    }
}

__global__ void agg1_k(const double* __restrict__ t4, const double* __restrict__ dis,
                       const int* __restrict__ deg, const int* __restrict__ csr,
                       const float* __restrict__ b4, double* __restrict__ h4) {
    int v = blockIdx.x * 256 + threadIdx.x;
    if (v >= Nn) return;
    int dv = min(deg[v], CAP);
    double dsv = dis[v];
    double acc = 0.0;
    const int* row = csr + (size_t)v * CAP;
    for (int j = 0; j < dv; ++j) { int u = row[j]; acc += dis[u] * t4[u]; }
    acc += dsv * t4[v];
    h4[v] = tanh((double)b4[0] + dsv * acc);
}

// ------- per-graph stable top-300 sort on fp64 keys (bitonic, 512 in LDS) -------
__global__ __launch_bounds__(512) void sort_k(const double* __restrict__ h4,
                                              int* __restrict__ order) {
    __shared__ unsigned long long kv[512];
    __shared__ int ki[512];
    int tid = threadIdx.x, g = blockIdx.x;
    unsigned long long key = ~0ull;
    if (tid < 400) {
        unsigned long long u = (unsigned long long)__double_as_longlong(h4[g * 400 + tid]);
        u = (u & 0x8000000000000000ull) ? ~u : (u | 0x8000000000000000ull); // asc map
        key = ~u;                                                           // descending
    }
    kv[tid] = key; ki[tid] = tid;
    __syncthreads();
    for (int size = 2; size <= 512; size <<= 1) {
        for (int stride = size >> 1; stride > 0; stride >>= 1) {
            int p = tid ^ stride;
            if (p > tid) {
                bool asc = ((tid & size) == 0);
                unsigned long long a = kv[tid], b = kv[p];
                int ia = ki[tid], ib = ki[p];
                bool gt = (a > b) || (a == b && ia > ib);   // stable tie-break
                if (gt == asc) { kv[tid] = b; kv[p] = a; ki[tid] = ib; ki[p] = ia; }
            }
            __syncthreads();
        }
    }
    if (tid < Kk) order[g * Kk + tid] = ki[tid];
}

// ---------------- conv1: z1[b,c,k] = relu(cb1[c] + sum_d feat[n,d]*cw1[c,d]) ----
__global__ __launch_bounds__(128) void conv1_k(const double* __restrict__ h1,
                                               const double* __restrict__ h2,
                                               const double* __restrict__ h3,
                                               const double* __restrict__ h4,
                                               const int* __restrict__ order,
                                               const float* __restrict__ cw1,
                                               const float* __restrict__ cb1,
                                               float* __restrict__ z1) {
    __shared__ double wt[193 * 16];   // transposed [d][c]
    int tid = threadIdx.x, b = blockIdx.y;
    for (int i = tid; i < 193 * 16; i += 128) {
        int c = i / 193, d = i % 193;
        wt[d * 16 + c] = (double)cw1[i];
    }
    __syncthreads();
    int kpos = blockIdx.x * 128 + tid;
    if (kpos >= Kk) return;
    int n = b * 400 + order[b * Kk + kpos];
    double acc[16];
#pragma unroll
    for (int c = 0; c < 16; ++c) acc[c] = (double)cb1[c];
    const double* bases[3] = {h1 + (size_t)n * 64, h2 + (size_t)n * 64, h3 + (size_t)n * 64};
    for (int r = 0; r < 3; ++r) {
        const double* p = bases[r];
        for (int d = 0; d < 64; ++d) {
            double xv = p[d];
            const double* wp = &wt[((size_t)r * 64 + d) * 16];
#pragma unroll
            for (int c = 0; c < 16; ++c) acc[c] += xv * wp[c];
        }
    }
    double xl = h4[n];
    {
        const double* wp = &wt[192 * 16];
#pragma unroll
        for (int c = 0; c < 16; ++c) acc[c] += xl * wp[c];
    }
#pragma unroll
    for (int c = 0; c < 16; ++c)
        z1[((size_t)b * 16 + c) * 300 + kpos] = (float)fmax(acc[c], 0.0);
}

// ------- fused tail: maxpool/2 -> conv2(16->32,k5)+relu -> MLP, per graph ------
__global__ __launch_bounds__(256) void tail_k(const float* __restrict__ z1,
                                              const float* __restrict__ cw2,
                                              const float* __restrict__ cb2,
                                              const float* __restrict__ mw1,
                                              const float* __restrict__ mb1,
                                              const float* __restrict__ mw2,
                                              const float* __restrict__ mb2,
                                              float* __restrict__ out) {
    __shared__ float lz[16 * 150];
    __shared__ float lw[2560];
    __shared__ float lz3[4672];
    __shared__ double red[256];
    __shared__ double s4[32];
    int b = blockIdx.x, tid = threadIdx.x;
    for (int i = tid; i < 2400; i += 256) {
        int bc = i / 150, j = i % 150;
        const float* zp = z1 + ((size_t)b * 16 + bc) * 300 + 2 * j;
        lz[i] = fmaxf(zp[0], zp[1]);
    }
    for (int i = tid; i < 2560; i += 256) lw[i] = cw2[i];
    __syncthreads();
    for (int o = tid; o < 4672; o += 256) {
        int co = o / 146, j = o % 146;
        float acc = cb2[co];
#pragma unroll
        for (int ci = 0; ci < 16; ++ci)
#pragma unroll
            for (int tt = 0; tt < 5; ++tt)
                acc += lz[ci * 150 + j + tt] * lw[co * 80 + ci * 5 + tt];
        lz3[o] = fmaxf(acc, 0.f);
    }
    __syncthreads();
    int o = tid & 31, part = tid >> 5;   // 8 parts x 584
    double acc = 0.0;
    for (int i = part * 584; i < (part + 1) * 584; ++i)
        acc += (double)lz3[i] * (double)mw1[(size_t)i * 32 + o];
    red[tid] = acc;
    __syncthreads();
    if (tid < 32) {
        double s = 0.0;
#pragma unroll
        for (int p = 0; p < 8; ++p) s += red[p * 32 + tid];
        s4[tid] = fmax(s + (double)mb1[tid], 0.0);
    }
    __syncthreads();
    if (tid < 2) {
        double s = (double)mb2[tid];
#pragma unroll
        for (int j = 0; j < 32; ++j) s += s4[j] * (double)mw2[j * 2 + tid];
        out[b * 2 + tid] = (float)s;
    }
}

extern "C" void kernel_launch(void* const* d_in, const int* in_sizes, int n_in,
                              void* d_out, int out_size, void* d_ws, size_t ws_size,
                              hipStream_t stream) {
    const float* x   = (const float*)d_in[0];
    const int*   ei  = (const int*)d_in[1];
    const float* W1  = (const float*)d_in[2];  const float* b1  = (const float*)d_in[3];
    const float* W2  = (const float*)d_in[4];  const float* b2  = (const float*)d_in[5];
    const float* W3  = (const float*)d_in[6];  const float* b3  = (const float*)d_in[7];
    const float* W4  = (const float*)d_in[8];  const float* b4  = (const float*)d_in[9];
    const float* cw1 = (const float*)d_in[10]; const float* cb1 = (const float*)d_in[11];
    const float* cw2 = (const float*)d_in[12]; const float* cb2 = (const float*)d_in[13];
    const float* mw1 = (const float*)d_in[14]; const float* mb1 = (const float*)d_in[15];
    const float* mw2 = (const float*)d_in[16]; const float* mb2 = (const float*)d_in[17];
    float* out = (float*)d_out;

    const size_t N64 = (size_t)Nn * 64;
    double* t   = (double*)d_ws;          // [N,64] transform scratch (fp64)
    double* h1  = t + N64;
    double* h2  = h1 + N64;
    double* h3  = h2 + N64;
    double* t4  = h3 + N64;               // [N]
    double* h4  = t4 + Nn;                // [N]
    double* dis = h4 + Nn;                // [N]
    int*   fill = (int*)(dis + Nn);       // degree (== atomic fill counter)
    int*   csr  = fill + Nn;              // [N,CAP]
    int*   order = csr + (size_t)Nn * CAP;
    float* z1 = (float*)t;                // aliases t (free after agg3 consumed it)

    hipMemsetAsync(fill, 0, sizeof(int) * (size_t)Nn, stream);

    scat_k<<<Ee / 256, 256, 0, stream>>>(ei, fill, csr);
    sortrow_k<<<Nn / 4, 256, 0, stream>>>(fill, csr, dis);   // + dis compute

    gemm_db<float, 25> <<<Nn / 64, 256, 0, stream>>>(x, W1, t);
    agg64_k<<<Nn / 4, 256, 0, stream>>>(t, b1, dis, fill, csr, h1, nullptr, nullptr);
    gemm_db<double, 4><<<Nn / 64, 256, 0, stream>>>(h1, W2, t);
    agg64_k<<<Nn / 4, 256, 0, stream>>>(t, b2, dis, fill, csr, h2, nullptr, nullptr);
    gemm_db<double, 4><<<Nn / 64, 256, 0, stream>>>(h2, W3, t);
    agg64_k<<<Nn / 4, 256, 0, stream>>>(t, b3, dis, fill, csr, h3, W4, t4);  // fused trans4

    agg1_k<<<Nn / 256, 256, 0, stream>>>(t4, dis, fill, csr, b4, h4);

    sort_k<<<Bb, 512, 0, stream>>>(h4, order);
    conv1_k<<<dim3(3, Bb), 128, 0, stream>>>(h1, h2, h3, h4, order, cw1, cb1, z1);
    tail_k<<<Bb, 256, 0, stream>>>(z1, cw2, cb2, mw1, mb1, mw2, mb2, out);
}

// Round 9
// 1093.481 us; speedup vs baseline: 1.3445x; 1.3445x over previous
//
#include <hip/hip_runtime.h>
#include <cstdint>
#include <cstddef>

#define Nn 102400
#define Ff 400
#define Ee 1638400
#define Kk 300
#define Bb 256
#define CAP 64

// ---------------- CSR build: fill counts degree; csr rows filled atomically ----
__global__ void scat_k(const int* __restrict__ ei, int* __restrict__ fill,
                       int* __restrict__ csr) {
    int e = blockIdx.x * 256 + threadIdx.x;
    if (e >= Ee) return;
    int s = ei[e], d = ei[Ee + e];
    int p = atomicAdd(&fill[d], 1);
    if (p < CAP) csr[(size_t)d * CAP + p] = s;
}

// Deterministic row order + dis computation (deg == fill after scat_k).
__global__ __launch_bounds__(256) void sortrow_k(const int* __restrict__ deg,
                                                 int* __restrict__ csr,
                                                 double* __restrict__ dis) {
    int lane = threadIdx.x & 63;
    int v = blockIdx.x * 4 + (threadIdx.x >> 6);
    int dvf = deg[v];
    int dv = min(dvf, CAP);
    if (lane == 0) dis[v] = 1.0 / sqrt((double)(dvf + 1));   // +1 self loop
    int key = (lane < dv) ? csr[(size_t)v * CAP + lane] : 0x7FFFFFFF;
#pragma unroll
    for (int k = 2; k <= 64; k <<= 1) {
#pragma unroll
        for (int j = k >> 1; j; j >>= 1) {
            int other = __shfl_xor(key, j);
            bool up = ((lane & k) == 0);
            bool lower = ((lane & j) == 0);
            key = (lower == up) ? min(key, other) : max(key, other);
        }
    }
    if (lane < dv) csr[(size_t)v * CAP + lane] = key;
}

// ---- thread-tile GEMM (R7 structure, proven at the fp64-FMA floor):
// [M,K]@[K,64] fp64 accumulate, 64x64 tile, 128 thr, 8x4/thread.
// A staged in SOURCE precision: f32 layer 1 (exact cvt at read) -> staging
// writes ds_write_b32 conflict-free, A reads 2xb128 instead of 4xb128.
// Per output strictly one fma per k, ascending -> h-chain bit-identical.
template <typename AT, int CH>   // K = 16*CH
__global__ __launch_bounds__(128) void gemm_t84(const AT* __restrict__ A,
                                                const float* __restrict__ B,
                                                double* __restrict__ C) {
    constexpr int K = 16 * CH;
    constexpr bool F32 = (sizeof(AT) == 4);
    __shared__ __align__(16) AT As[16][64];
    __shared__ __align__(16) double Bs[16][65];
    int tid = threadIdx.x;
    int tx = tid & 15;            // cols {tx*2, tx*2+1, 32+tx*2, 33+tx*2}
    int ty = tid >> 4;            // rows ty*8..+7
    int base = blockIdx.x * 64;
    int sr = tid >> 1, sh = tid & 1;       // A staging: row sr, k-half sh
    int bk = tid >> 3, bn = (tid & 7) * 8; // B staging
    double acc[8][4] = {};
    for (int ch = 0; ch < CH; ++ch) {
        int k0 = ch * 16;
        AT a8[8];
        const AT* ap = A + (size_t)(base + sr) * K + k0 + sh * 8;
        if constexpr (F32) {
            float4 v0 = *(const float4*)(ap);
            float4 v1 = *(const float4*)(ap + 4);
            a8[0] = v0.x; a8[1] = v0.y; a8[2] = v0.z; a8[3] = v0.w;
            a8[4] = v1.x; a8[5] = v1.y; a8[6] = v1.z; a8[7] = v1.w;
        } else {
            double2 d0 = *(const double2*)(ap);
            double2 d1 = *(const double2*)(ap + 2);
            double2 d2 = *(const double2*)(ap + 4);
            double2 d3 = *(const double2*)(ap + 6);
            a8[0] = d0.x; a8[1] = d0.y; a8[2] = d1.x; a8[3] = d1.y;
            a8[4] = d2.x; a8[5] = d2.y; a8[6] = d3.x; a8[7] = d3.y;
        }
        float4 b0 = *(const float4*)(B + (size_t)(k0 + bk) * 64 + bn);
        float4 b1 = *(const float4*)(B + (size_t)(k0 + bk) * 64 + bn + 4);
        __syncthreads();
#pragma unroll
        for (int q = 0; q < 8; ++q) As[sh * 8 + q][sr] = a8[q];
        Bs[bk][bn + 0] = (double)b0.x; Bs[bk][bn + 1] = (double)b0.y;
        Bs[bk][bn + 2] = (double)b0.z; Bs[bk][bn + 3] = (double)b0.w;
        Bs[bk][bn + 4] = (double)b1.x; Bs[bk][bn + 5] = (double)b1.y;
        Bs[bk][bn + 6] = (double)b1.z; Bs[bk][bn + 7] = (double)b1.w;
        __syncthreads();
#pragma unroll
        for (int kk = 0; kk < 16; ++kk) {
            double av[8];
            if constexpr (F32) {
                float4 f0 = *(const float4*)&As[kk][ty * 8];
                float4 f1 = *(const float4*)&As[kk][ty * 8 + 4];
                av[0] = f0.x; av[1] = f0.y; av[2] = f0.z; av[3] = f0.w;
                av[4] = f1.x; av[5] = f1.y; av[6] = f1.z; av[7] = f1.w;
            } else {
                double2 a01 = *(const double2*)&As[kk][ty * 8];
                double2 a23 = *(const double2*)&As[kk][ty * 8 + 2];
                double2 a45 = *(const double2*)&As[kk][ty * 8 + 4];
                double2 a67 = *(const double2*)&As[kk][ty * 8 + 6];
                av[0] = a01.x; av[1] = a01.y; av[2] = a23.x; av[3] = a23.y;
                av[4] = a45.x; av[5] = a45.y; av[6] = a67.x; av[7] = a67.y;
            }
            double2 b01 = *(const double2*)&Bs[kk][tx * 2];
            double2 b23 = *(const double2*)&Bs[kk][32 + tx * 2];
            double bv[4] = {b01.x, b01.y, b23.x, b23.y};
#pragma unroll
            for (int r = 0; r < 8; ++r)
#pragma unroll
                for (int c = 0; c < 4; ++c) acc[r][c] += av[r] * bv[c];
        }
    }
#pragma unroll
    for (int r = 0; r < 8; ++r) {
        double* cp = C + (size_t)(base + ty * 8 + r) * 64;
        *(double2*)(cp + tx * 2)      = make_double2(acc[r][0], acc[r][1]);
        *(double2*)(cp + 32 + tx * 2) = make_double2(acc[r][2], acc[r][3]);
    }
}

// ------- out = tanh(bias + dsv*(sum_u du*t[u] + dsv*t[v])), 64-wide fp64 -------
// Unroll 8 (R7-proven; unroll 16 regressed via register pressure).
// fma order: j ascending, self-loop last — identical to all previous rounds.
__global__ __launch_bounds__(256) void agg64_k(const double* __restrict__ t,
                                               const float* __restrict__ bias,
                                               const double* __restrict__ dis,
                                               const int* __restrict__ deg,
                                               const int* __restrict__ csr,
                                               double* __restrict__ out,
                                               const float* __restrict__ W4,
                                               double* __restrict__ t4) {
    int lane = threadIdx.x & 63;
    int wv = __builtin_amdgcn_readfirstlane(threadIdx.x >> 6);
    int v = blockIdx.x * 4 + wv;
    int dv = min(deg[v], CAP);
    double dsv = dis[v];
    const int* row = csr + (size_t)v * CAP;
    double acc = 0.0;
    int j = 0;
    for (; j + 8 <= dv; j += 8) {
        int u[8]; double d[8], tv[8];
#pragma unroll
        for (int q = 0; q < 8; ++q) u[q] = row[j + q];
#pragma unroll
        for (int q = 0; q < 8; ++q) tv[q] = t[(size_t)u[q] * 64 + lane];
#pragma unroll
        for (int q = 0; q < 8; ++q) d[q] = dis[u[q]];
#pragma unroll
        for (int q = 0; q < 8; ++q) acc += d[q] * tv[q];
    }
    for (; j < dv; ++j) {
        int u = row[j];
        acc += dis[u] * t[(size_t)u * 64 + lane];
    }
    acc += dsv * t[(size_t)v * 64 + lane];   // self-loop last (ref appends loops)
    double res = tanh((double)bias[lane] + dsv * acc);
    out[(size_t)v * 64 + lane] = res;
    if (t4 != nullptr) {
        double x = res * (double)W4[lane];
#pragma unroll
        for (int o = 32; o > 0; o >>= 1) x += __shfl_xor(x, o);
        if (lane == 0) t4[v] = x;
    }
}

__global__ void agg1_k(const double* __restrict__ t4, const double* __restrict__ dis,
                       const int* __restrict__ deg, const int* __restrict__ csr,
                       const float* __restrict__ b4, double* __restrict__ h4) {
    int v = blockIdx.x * 256 + threadIdx.x;
    if (v >= Nn) return;
    int dv = min(deg[v], CAP);
    double dsv = dis[v];
    double acc = 0.0;
    const int* row = csr + (size_t)v * CAP;
    for (int j = 0; j < dv; ++j) { int u = row[j]; acc += dis[u] * t4[u]; }
    acc += dsv * t4[v];
    h4[v] = tanh((double)b4[0] + dsv * acc);
}

// ------- per-graph stable top-300 sort on fp64 keys (bitonic, 512 in LDS) -------
__global__ __launch_bounds__(512) void sort_k(const double* __restrict__ h4,
                                              int* __restrict__ order) {
    __shared__ unsigned long long kv[512];
    __shared__ int ki[512];
    int tid = threadIdx.x, g = blockIdx.x;
    unsigned long long key = ~0ull;
    if (tid < 400) {
        unsigned long long u = (unsigned long long)__double_as_longlong(h4[g * 400 + tid]);
        u = (u & 0x8000000000000000ull) ? ~u : (u | 0x8000000000000000ull); // asc map
        key = ~u;                                                           // descending
    }
    kv[tid] = key; ki[tid] = tid;
    __syncthreads();
    for (int size = 2; size <= 512; size <<= 1) {
        for (int stride = size >> 1; stride > 0; stride >>= 1) {
            int p = tid ^ stride;
            if (p > tid) {
                bool asc = ((tid & size) == 0);
                unsigned long long a = kv[tid], b = kv[p];
                int ia = ki[tid], ib = ki[p];
                bool gt = (a > b) || (a == b && ia > ib);   // stable tie-break
                if (gt == asc) { kv[tid] = b; kv[p] = a; ki[tid] = ib; ki[p] = ia; }
            }
            __syncthreads();
        }
    }
    if (tid < Kk) order[g * Kk + tid] = ki[tid];
}

// ---------------- conv1: z1[b,c,k] = relu(cb1[c] + sum_d feat[n,d]*cw1[c,d]) ----
__global__ __launch_bounds__(128) void conv1_k(const double* __restrict__ h1,
                                               const double* __restrict__ h2,
                                               const double* __restrict__ h3,
                                               const double* __restrict__ h4,
                                               const int* __restrict__ order,
                                               const float* __restrict__ cw1,
                                               const float* __restrict__ cb1,
                                               float* __restrict__ z1) {
    __shared__ double wt[193 * 16];   // transposed [d][c]
    int tid = threadIdx.x, b = blockIdx.y;
    for (int i = tid; i < 193 * 16; i += 128) {
        int c = i / 193, d = i % 193;
        wt[d * 16 + c] = (double)cw1[i];
    }
    __syncthreads();
    int kpos = blockIdx.x * 128 + tid;
    if (kpos >= Kk) return;
    int n = b * 400 + order[b * Kk + kpos];
    double acc[16];
#pragma unroll
    for (int c = 0; c < 16; ++c) acc[c] = (double)cb1[c];
    const double* bases[3] = {h1 + (size_t)n * 64, h2 + (size_t)n * 64, h3 + (size_t)n * 64};
    for (int r = 0; r < 3; ++r) {
        const double* p = bases[r];
        for (int d = 0; d < 64; ++d) {
            double xv = p[d];
            const double* wp = &wt[((size_t)r * 64 + d) * 16];
#pragma unroll
            for (int c = 0; c < 16; ++c) acc[c] += xv * wp[c];
        }
    }
    double xl = h4[n];
    {
        const double* wp = &wt[192 * 16];
#pragma unroll
        for (int c = 0; c < 16; ++c) acc[c] += xl * wp[c];
    }
#pragma unroll
    for (int c = 0; c < 16; ++c)
        z1[((size_t)b * 16 + c) * 300 + kpos] = (float)fmax(acc[c], 0.0);
}

// ------- fused tail: maxpool/2 -> conv2(16->32,k5)+relu -> MLP, per graph ------
__global__ __launch_bounds__(256) void tail_k(const float* __restrict__ z1,
                                              const float* __restrict__ cw2,
                                              const float* __restrict__ cb2,
                                              const float* __restrict__ mw1,
                                              const float* __restrict__ mb1,
                                              const float* __restrict__ mw2,
                                              const float* __restrict__ mb2,
                                              float* __restrict__ out) {
    __shared__ float lz[16 * 150];
    __shared__ float lw[2560];
    __shared__ float lz3[4672];
    __shared__ double red[256];
    __shared__ double s4[32];
    int b = blockIdx.x, tid = threadIdx.x;
    for (int i = tid; i < 2400; i += 256) {
        int bc = i / 150, j = i % 150;
        const float* zp = z1 + ((size_t)b * 16 + bc) * 300 + 2 * j;
        lz[i] = fmaxf(zp[0], zp[1]);
    }
    for (int i = tid; i < 2560; i += 256) lw[i] = cw2[i];
    __syncthreads();
    for (int o = tid; o < 4672; o += 256) {
        int co = o / 146, j = o % 146;
        float acc = cb2[co];
#pragma unroll
        for (int ci = 0; ci < 16; ++ci)
#pragma unroll
            for (int tt = 0; tt < 5; ++tt)
                acc += lz[ci * 150 + j + tt] * lw[co * 80 + ci * 5 + tt];
        lz3[o] = fmaxf(acc, 0.f);
    }
    __syncthreads();
    int o = tid & 31, part = tid >> 5;   // 8 parts x 584
    double acc = 0.0;
    for (int i = part * 584; i < (part + 1) * 584; ++i)
        acc += (double)lz3[i] * (double)mw1[(size_t)i * 32 + o];
    red[tid] = acc;
    __syncthreads();
    if (tid < 32) {
        double s = 0.0;
#pragma unroll
        for (int p = 0; p < 8; ++p) s += red[p * 32 + tid];
        s4[tid] = fmax(s + (double)mb1[tid], 0.0);
    }
    __syncthreads();
    if (tid < 2) {
        double s = (double)mb2[tid];
#pragma unroll
        for (int j = 0; j < 32; ++j) s += s4[j] * (double)mw2[j * 2 + tid];
        out[b * 2 + tid] = (float)s;
    }
}

extern "C" void kernel_launch(void* const* d_in, const int* in_sizes, int n_in,
                              void* d_out, int out_size, void* d_ws, size_t ws_size,
                              hipStream_t stream) {
    const float* x   = (const float*)d_in[0];
    const int*   ei  = (const int*)d_in[1];
    const float* W1  = (const float*)d_in[2];  const float* b1  = (const float*)d_in[3];
    const float* W2  = (const float*)d_in[4];  const float* b2  = (const float*)d_in[5];
    const float* W3  = (const float*)d_in[6];  const float* b3  = (const float*)d_in[7];
    const float* W4  = (const float*)d_in[8];  const float* b4  = (const float*)d_in[9];
    const float* cw1 = (const float*)d_in[10]; const float* cb1 = (const float*)d_in[11];
    const float* cw2 = (const float*)d_in[12]; const float* cb2 = (const float*)d_in[13];
    const float* mw1 = (const float*)d_in[14]; const float* mb1 = (const float*)d_in[15];
    const float* mw2 = (const float*)d_in[16]; const float* mb2 = (const float*)d_in[17];
    float* out = (float*)d_out;

    const size_t N64 = (size_t)Nn * 64;
    double* t   = (double*)d_ws;          // [N,64] transform scratch (fp64)
    double* h1  = t + N64;
    double* h2  = h1 + N64;
    double* h3  = h2 + N64;
    double* t4  = h3 + N64;               // [N]
    double* h4  = t4 + Nn;                // [N]
    double* dis = h4 + Nn;                // [N]
    int*   fill = (int*)(dis + Nn);       // degree (== atomic fill counter)
    int*   csr  = fill + Nn;              // [N,CAP]
    int*   order = csr + (size_t)Nn * CAP;
    float* z1 = (float*)t;                // aliases t (free after agg3 consumed it)

    hipMemsetAsync(fill, 0, sizeof(int) * (size_t)Nn, stream);

    scat_k<<<Ee / 256, 256, 0, stream>>>(ei, fill, csr);
    sortrow_k<<<Nn / 4, 256, 0, stream>>>(fill, csr, dis);   // + dis compute

    gemm_t84<float, 25> <<<Nn / 64, 128, 0, stream>>>(x, W1, t);
    agg64_k<<<Nn / 4, 256, 0, stream>>>(t, b1, dis, fill, csr, h1, nullptr, nullptr);
    gemm_t84<double, 4><<<Nn / 64, 128, 0, stream>>>(h1, W2, t);
    agg64_k<<<Nn / 4, 256, 0, stream>>>(t, b2, dis, fill, csr, h2, nullptr, nullptr);
    gemm_t84<double, 4><<<Nn / 64, 128, 0, stream>>>(h2, W3, t);
    agg64_k<<<Nn / 4, 256, 0, stream>>>(t, b3, dis, fill, csr, h3, W4, t4);  // fused trans4

    agg1_k<<<Nn / 256, 256, 0, stream>>>(t4, dis, fill, csr, b4, h4);

    sort_k<<<Bb, 512, 0, stream>>>(h4, order);
    conv1_k<<<dim3(3, Bb), 128, 0, stream>>>(h1, h2, h3, h4, order, cw1, cb1, z1);
    tail_k<<<Bb, 256, 0, stream>>>(z1, cw2, cb2, mw1, mb1, mw2, mb2, out);
}

// Round 10
// 1093.427 us; speedup vs baseline: 1.3446x; 1.0000x over previous
//
#include <hip/hip_runtime.h>
#include <cstdint>
#include <cstddef>

#define Nn 102400
#define Ff 400
#define Ee 1638400
#define Kk 300
#define Bb 256
#define CAP 64

// ---------------- CSR build: fill counts degree; csr rows filled atomically ----
__global__ void scat_k(const int* __restrict__ ei, int* __restrict__ fill,
                       int* __restrict__ csr) {
    int e = blockIdx.x * 256 + threadIdx.x;
    if (e >= Ee) return;
    int s = ei[e], d = ei[Ee + e];
    int p = atomicAdd(&fill[d], 1);
    if (p < CAP) csr[(size_t)d * CAP + p] = s;
}

// Deterministic row order + dis computation (deg == fill after scat_k).
__global__ __launch_bounds__(256) void sortrow_k(const int* __restrict__ deg,
                                                 int* __restrict__ csr,
                                                 double* __restrict__ dis) {
    int lane = threadIdx.x & 63;
    int v = blockIdx.x * 4 + (threadIdx.x >> 6);
    int dvf = deg[v];
    int dv = min(dvf, CAP);
    if (lane == 0) dis[v] = 1.0 / sqrt((double)(dvf + 1));   // +1 self loop
    int key = (lane < dv) ? csr[(size_t)v * CAP + lane] : 0x7FFFFFFF;
#pragma unroll
    for (int k = 2; k <= 64; k <<= 1) {
#pragma unroll
        for (int j = k >> 1; j; j >>= 1) {
            int other = __shfl_xor(key, j);
            bool up = ((lane & k) == 0);
            bool lower = ((lane & j) == 0);
            key = (lower == up) ? min(key, other) : max(key, other);
        }
    }
    if (lane < dv) csr[(size_t)v * CAP + lane] = key;
}

// ---- single-wave GEMM: [M,K]@[K,64] fp64 accumulate, 32x64 tile, 64 thr,
// 8x4/thread. Workgroup == 1 wave: __syncthreads() lowers to s_waitcnt only
// (no s_barrier drain — the structural stall of the 2-barrier K-loop).
// Grid 3200 = 12.5 blocks/CU. A staged in source precision (exact cvt at
// read). Per output strictly one fma per k, ascending -> bit-identical.
template <typename AT, int CH>   // K = 16*CH
__global__ __launch_bounds__(64) void gemm_w32(const AT* __restrict__ A,
                                               const float* __restrict__ B,
                                               double* __restrict__ C) {
    constexpr int K = 16 * CH;
    constexpr bool F32 = (sizeof(AT) == 4);
    constexpr int APD = F32 ? 32 : 33;
    __shared__ __align__(16) AT As[16 * APD];
    __shared__ __align__(16) double Bs[16][65];
    int tid = threadIdx.x;
    int tx = tid & 15;            // cols {tx*2, tx*2+1, 32+tx*2, 33+tx*2}
    int ty = tid >> 4;            // rows ty*8..+7 (0..3)
    int base = blockIdx.x * 32;
    int sr = tid >> 1, sh = tid & 1;        // A staging: row sr(0..31), k-half sh
    int bk = tid >> 2, bn = (tid & 3) * 16; // B staging: k-row bk(0..15), 16 cols
    double acc[8][4] = {};
    for (int ch = 0; ch < CH; ++ch) {
        int k0 = ch * 16;
        AT a8[8];
        const AT* ap = A + (size_t)(base + sr) * K + k0 + sh * 8;
        if constexpr (F32) {
            float4 v0 = *(const float4*)(ap);
            float4 v1 = *(const float4*)(ap + 4);
            a8[0] = v0.x; a8[1] = v0.y; a8[2] = v0.z; a8[3] = v0.w;
            a8[4] = v1.x; a8[5] = v1.y; a8[6] = v1.z; a8[7] = v1.w;
        } else {
            double2 d0 = *(const double2*)(ap);
            double2 d1 = *(const double2*)(ap + 2);
            double2 d2 = *(const double2*)(ap + 4);
            double2 d3 = *(const double2*)(ap + 6);
            a8[0] = d0.x; a8[1] = d0.y; a8[2] = d1.x; a8[3] = d1.y;
            a8[4] = d2.x; a8[5] = d2.y; a8[6] = d3.x; a8[7] = d3.y;
        }
        float4 bv4[4];
        const float* bp = B + (size_t)(k0 + bk) * 64 + bn;
#pragma unroll
        for (int q = 0; q < 4; ++q) bv4[q] = *(const float4*)(bp + q * 4);
        __syncthreads();   // wave-level: s_waitcnt only
#pragma unroll
        for (int q = 0; q < 8; ++q) As[(sh * 8 + q) * APD + sr] = a8[q];
#pragma unroll
        for (int q = 0; q < 4; ++q) {
            Bs[bk][bn + q * 4 + 0] = (double)bv4[q].x;
            Bs[bk][bn + q * 4 + 1] = (double)bv4[q].y;
            Bs[bk][bn + q * 4 + 2] = (double)bv4[q].z;
            Bs[bk][bn + q * 4 + 3] = (double)bv4[q].w;
        }
        __syncthreads();
#pragma unroll
        for (int kk = 0; kk < 16; ++kk) {
            double av[8];
            if constexpr (F32) {
                float4 f0 = *(const float4*)&As[kk * APD + ty * 8];
                float4 f1 = *(const float4*)&As[kk * APD + ty * 8 + 4];
                av[0] = f0.x; av[1] = f0.y; av[2] = f0.z; av[3] = f0.w;
                av[4] = f1.x; av[5] = f1.y; av[6] = f1.z; av[7] = f1.w;
            } else {
                double2 a01 = *(const double2*)&As[kk * APD + ty * 8];
                double2 a23 = *(const double2*)&As[kk * APD + ty * 8 + 2];
                double2 a45 = *(const double2*)&As[kk * APD + ty * 8 + 4];
                double2 a67 = *(const double2*)&As[kk * APD + ty * 8 + 6];
                av[0] = a01.x; av[1] = a01.y; av[2] = a23.x; av[3] = a23.y;
                av[4] = a45.x; av[5] = a45.y; av[6] = a67.x; av[7] = a67.y;
            }
            double2 b01 = *(const double2*)&Bs[kk][tx * 2];
            double2 b23 = *(const double2*)&Bs[kk][32 + tx * 2];
            double bv[4] = {b01.x, b01.y, b23.x, b23.y};
#pragma unroll
            for (int r = 0; r < 8; ++r)
#pragma unroll
                for (int c = 0; c < 4; ++c) acc[r][c] += av[r] * bv[c];
        }
    }
#pragma unroll
    for (int r = 0; r < 8; ++r) {
        double* cp = C + (size_t)(base + ty * 8 + r) * 64;
        *(double2*)(cp + tx * 2)      = make_double2(acc[r][0], acc[r][1]);
        *(double2*)(cp + 32 + tx * 2) = make_double2(acc[r][2], acc[r][3]);
    }
}

// ------- out = tanh(bias + dsv*(sum_u du*t[u] + dsv*t[v])), 64-wide fp64 -------
// readfirstlane forces row indices / dis through the scalar path (SGPRs),
// freeing VGPRs so 16 t-row gathers stay in flight (R8's unroll-16 failed on
// VGPR pressure). fma order: j ascending, self-loop last — unchanged.
__global__ __launch_bounds__(256) void agg64_k(const double* __restrict__ t,
                                               const float* __restrict__ bias,
                                               const double* __restrict__ dis,
                                               const int* __restrict__ deg,
                                               const int* __restrict__ csr,
                                               double* __restrict__ out,
                                               const float* __restrict__ W4,
                                               double* __restrict__ t4) {
    int lane = threadIdx.x & 63;
    int wv = __builtin_amdgcn_readfirstlane(threadIdx.x >> 6);
    int v = blockIdx.x * 4 + wv;
    int dv = min(deg[v], CAP);
    double dsv = dis[v];
    const int* row = csr + (size_t)v * CAP;
    double acc = 0.0;
    int j = 0;
    for (; j + 16 <= dv; j += 16) {
        int u[16]; double d[16], tv[16];
#pragma unroll
        for (int q = 0; q < 16; ++q) u[q] = __builtin_amdgcn_readfirstlane(row[j + q]);
#pragma unroll
        for (int q = 0; q < 16; ++q) tv[q] = t[(size_t)u[q] * 64 + lane];
#pragma unroll
        for (int q = 0; q < 16; ++q) d[q] = dis[u[q]];
#pragma unroll
        for (int q = 0; q < 16; ++q) acc += d[q] * tv[q];
    }
    for (; j + 4 <= dv; j += 4) {
        int u[4]; double d[4], tv[4];
#pragma unroll
        for (int q = 0; q < 4; ++q) u[q] = __builtin_amdgcn_readfirstlane(row[j + q]);
#pragma unroll
        for (int q = 0; q < 4; ++q) tv[q] = t[(size_t)u[q] * 64 + lane];
#pragma unroll
        for (int q = 0; q < 4; ++q) d[q] = dis[u[q]];
#pragma unroll
        for (int q = 0; q < 4; ++q) acc += d[q] * tv[q];
    }
    for (; j < dv; ++j) {
        int u = __builtin_amdgcn_readfirstlane(row[j]);
        acc += dis[u] * t[(size_t)u * 64 + lane];
    }
    acc += dsv * t[(size_t)v * 64 + lane];   // self-loop last (ref appends loops)
    double res = tanh((double)bias[lane] + dsv * acc);
    out[(size_t)v * 64 + lane] = res;
    if (t4 != nullptr) {
        double x = res * (double)W4[lane];
#pragma unroll
        for (int o = 32; o > 0; o >>= 1) x += __shfl_xor(x, o);
        if (lane == 0) t4[v] = x;
    }
}

__global__ void agg1_k(const double* __restrict__ t4, const double* __restrict__ dis,
                       const int* __restrict__ deg, const int* __restrict__ csr,
                       const float* __restrict__ b4, double* __restrict__ h4) {
    int v = blockIdx.x * 256 + threadIdx.x;
    if (v >= Nn) return;
    int dv = min(deg[v], CAP);
    double dsv = dis[v];
    double acc = 0.0;
    const int* row = csr + (size_t)v * CAP;
    for (int j = 0; j < dv; ++j) { int u = row[j]; acc += dis[u] * t4[u]; }
    acc += dsv * t4[v];
    h4[v] = tanh((double)b4[0] + dsv * acc);
}

// ------- per-graph stable top-300 sort on fp64 keys (bitonic, 512 in LDS) -------
__global__ __launch_bounds__(512) void sort_k(const double* __restrict__ h4,
                                              int* __restrict__ order) {
    __shared__ unsigned long long kv[512];
    __shared__ int ki[512];
    int tid = threadIdx.x, g = blockIdx.x;
    unsigned long long key = ~0ull;
    if (tid < 400) {
        unsigned long long u = (unsigned long long)__double_as_longlong(h4[g * 400 + tid]);
        u = (u & 0x8000000000000000ull) ? ~u : (u | 0x8000000000000000ull); // asc map
        key = ~u;                                                           // descending
    }
    kv[tid] = key; ki[tid] = tid;
    __syncthreads();
    for (int size = 2; size <= 512; size <<= 1) {
        for (int stride = size >> 1; stride > 0; stride >>= 1) {
            int p = tid ^ stride;
            if (p > tid) {
                bool asc = ((tid & size) == 0);
                unsigned long long a = kv[tid], b = kv[p];
                int ia = ki[tid], ib = ki[p];
                bool gt = (a > b) || (a == b && ia > ib);   // stable tie-break
                if (gt == asc) { kv[tid] = b; kv[p] = a; ki[tid] = ib; ki[p] = ia; }
            }
            __syncthreads();
        }
    }
    if (tid < Kk) order[g * Kk + tid] = ki[tid];
}

// ---------------- conv1: z1[b,c,k] = relu(cb1[c] + sum_d feat[n,d]*cw1[c,d]) ----
__global__ __launch_bounds__(128) void conv1_k(const double* __restrict__ h1,
                                               const double* __restrict__ h2,
                                               const double* __restrict__ h3,
                                               const double* __restrict__ h4,
                                               const int* __restrict__ order,
                                               const float* __restrict__ cw1,
                                               const float* __restrict__ cb1,
                                               float* __restrict__ z1) {
    __shared__ double wt[193 * 16];   // transposed [d][c]
    int tid = threadIdx.x, b = blockIdx.y;
    for (int i = tid; i < 193 * 16; i += 128) {
        int c = i / 193, d = i % 193;
        wt[d * 16 + c] = (double)cw1[i];
    }
    __syncthreads();
    int kpos = blockIdx.x * 128 + tid;
    if (kpos >= Kk) return;
    int n = b * 400 + order[b * Kk + kpos];
    double acc[16];
#pragma unroll
    for (int c = 0; c < 16; ++c) acc[c] = (double)cb1[c];
    const double* bases[3] = {h1 + (size_t)n * 64, h2 + (size_t)n * 64, h3 + (size_t)n * 64};
    for (int r = 0; r < 3; ++r) {
        const double* p = bases[r];
        for (int d = 0; d < 64; ++d) {
            double xv = p[d];
            const double* wp = &wt[((size_t)r * 64 + d) * 16];
#pragma unroll
            for (int c = 0; c < 16; ++c) acc[c] += xv * wp[c];
        }
    }
    double xl = h4[n];
    {
        const double* wp = &wt[192 * 16];
#pragma unroll
        for (int c = 0; c < 16; ++c) acc[c] += xl * wp[c];
    }
#pragma unroll
    for (int c = 0; c < 16; ++c)
        z1[((size_t)b * 16 + c) * 300 + kpos] = (float)fmax(acc[c], 0.0);
}

// ------- fused tail: maxpool/2 -> conv2(16->32,k5)+relu -> MLP, per graph ------
__global__ __launch_bounds__(256) void tail_k(const float* __restrict__ z1,
                                              const float* __restrict__ cw2,
                                              const float* __restrict__ cb2,
                                              const float* __restrict__ mw1,
                                              const float* __restrict__ mb1,
                                              const float* __restrict__ mw2,
                                              const float* __restrict__ mb2,
                                              float* __restrict__ out) {
    __shared__ float lz[16 * 150];
    __shared__ float lw[2560];
    __shared__ float lz3[4672];
    __shared__ double red[256];
    __shared__ double s4[32];
    int b = blockIdx.x, tid = threadIdx.x;
    for (int i = tid; i < 2400; i += 256) {
        int bc = i / 150, j = i % 150;
        const float* zp = z1 + ((size_t)b * 16 + bc) * 300 + 2 * j;
        lz[i] = fmaxf(zp[0], zp[1]);
    }
    for (int i = tid; i < 2560; i += 256) lw[i] = cw2[i];
    __syncthreads();
    for (int o = tid; o < 4672; o += 256) {
        int co = o / 146, j = o % 146;
        float acc = cb2[co];
#pragma unroll
        for (int ci = 0; ci < 16; ++ci)
#pragma unroll
            for (int tt = 0; tt < 5; ++tt)
                acc += lz[ci * 150 + j + tt] * lw[co * 80 + ci * 5 + tt];
        lz3[o] = fmaxf(acc, 0.f);
    }
    __syncthreads();
    int o = tid & 31, part = tid >> 5;   // 8 parts x 584
    double acc = 0.0;
    for (int i = part * 584; i < (part + 1) * 584; ++i)
        acc += (double)lz3[i] * (double)mw1[(size_t)i * 32 + o];
    red[tid] = acc;
    __syncthreads();
    if (tid < 32) {
        double s = 0.0;
#pragma unroll
        for (int p = 0; p < 8; ++p) s += red[p * 32 + tid];
        s4[tid] = fmax(s + (double)mb1[tid], 0.0);
    }
    __syncthreads();
    if (tid < 2) {
        double s = (double)mb2[tid];
#pragma unroll
        for (int j = 0; j < 32; ++j) s += s4[j] * (double)mw2[j * 2 + tid];
        out[b * 2 + tid] = (float)s;
    }
}

extern "C" void kernel_launch(void* const* d_in, const int* in_sizes, int n_in,
                              void* d_out, int out_size, void* d_ws, size_t ws_size,
                              hipStream_t stream) {
    const float* x   = (const float*)d_in[0];
    const int*   ei  = (const int*)d_in[1];
    const float* W1  = (const float*)d_in[2];  const float* b1  = (const float*)d_in[3];
    const float* W2  = (const float*)d_in[4];  const float* b2  = (const float*)d_in[5];
    const float* W3  = (const float*)d_in[6];  const float* b3  = (const float*)d_in[7];
    const float* W4  = (const float*)d_in[8];  const float* b4  = (const float*)d_in[9];
    const float* cw1 = (const float*)d_in[10]; const float* cb1 = (const float*)d_in[11];
    const float* cw2 = (const float*)d_in[12]; const float* cb2 = (const float*)d_in[13];
    const float* mw1 = (const float*)d_in[14]; const float* mb1 = (const float*)d_in[15];
    const float* mw2 = (const float*)d_in[16]; const float* mb2 = (const float*)d_in[17];
    float* out = (float*)d_out;

    const size_t N64 = (size_t)Nn * 64;
    double* t   = (double*)d_ws;          // [N,64] transform scratch (fp64)
    double* h1  = t + N64;
    double* h2  = h1 + N64;
    double* h3  = h2 + N64;
    double* t4  = h3 + N64;               // [N]
    double* h4  = t4 + Nn;                // [N]
    double* dis = h4 + Nn;                // [N]
    int*   fill = (int*)(dis + Nn);       // degree (== atomic fill counter)
    int*   csr  = fill + Nn;              // [N,CAP]
    int*   order = csr + (size_t)Nn * CAP;
    float* z1 = (float*)t;                // aliases t (free after agg3 consumed it)

    hipMemsetAsync(fill, 0, sizeof(int) * (size_t)Nn, stream);

    scat_k<<<Ee / 256, 256, 0, stream>>>(ei, fill, csr);
    sortrow_k<<<Nn / 4, 256, 0, stream>>>(fill, csr, dis);   // + dis compute

    gemm_w32<float, 25> <<<Nn / 32, 64, 0, stream>>>(x, W1, t);
    agg64_k<<<Nn / 4, 256, 0, stream>>>(t, b1, dis, fill, csr, h1, nullptr, nullptr);
    gemm_w32<double, 4><<<Nn / 32, 64, 0, stream>>>(h1, W2, t);
    agg64_k<<<Nn / 4, 256, 0, stream>>>(t, b2, dis, fill, csr, h2, nullptr, nullptr);
    gemm_w32<double, 4><<<Nn / 32, 64, 0, stream>>>(h2, W3, t);
    agg64_k<<<Nn / 4, 256, 0, stream>>>(t, b3, dis, fill, csr, h3, W4, t4);  // fused trans4

    agg1_k<<<Nn / 256, 256, 0, stream>>>(t4, dis, fill, csr, b4, h4);

    sort_k<<<Bb, 512, 0, stream>>>(h4, order);
    conv1_k<<<dim3(3, Bb), 128, 0, stream>>>(h1, h2, h3, h4, order, cw1, cb1, z1);
    tail_k<<<Bb, 256, 0, stream>>>(z1, cw2, cb2, mw1, mb1, mw2, mb2, out);
}